// Round 4
// baseline (583.914 us; speedup 1.0000x reference)
//
#include <hip/hip_runtime.h>
#include <hip/hip_bf16.h>

// out[csr[i]] += x[ptrs[i]]
//   X_SIZE = 8,388,608 f32 (32 MB), NNZ = 33,554,432, N_SEG = 8,388,608, csr SORTED.
//
// R3 post-mortem: FETCH = 2.04 GB vs 290 MB compulsory. 1.75 GB is gather
// capacity churn (random 4B picks from 32 MB through 4 MiB/XCD L2).
// Fix: stable 8-way binning by ptr slice (4 MB = one XCD's L2):
//   A: per-block bucket histogram          (read ptrs 128 MB)
//   B: per-bucket exclusive scan of A      (tiny)
//   C: stable partition -> (ptr,csr) pairs (read 256 MB, write 256 MB)
//   D: per-bucket gather (L2-resident slice, XCD-pinned via blockIdx%8)
//      + LDS run-length segment accumulate + atomic flush (buckets overlap)
// Stability in C preserves csr sortedness within each bucket => D keeps the
// run-length/LDS compaction. Falls back to the proven R3 kernel if d_ws is
// too small or shapes are irregular.

#define THREADS 256
#define PER_THREAD 16
#define EPB (THREADS * PER_THREAD)   // 4096 entries per block
#define NB 8                         // buckets = x slices of 4 MB
#define LDS_SEGS_FB 4096             // fallback kernel LDS span
#define LDS_SEGS_D 12288             // phase D LDS span (48 KB; mean 8192, +32 sigma)

typedef int vint4 __attribute__((ext_vector_type(4)));
typedef int vint2 __attribute__((ext_vector_type(2)));

// ---------------------------------------------------------------- Phase A
__global__ __launch_bounds__(THREADS) void phaseA_count(
    const int* __restrict__ ptrs, int* __restrict__ counts, int shift)
{
    __shared__ unsigned long long cLo, cHi;   // 16-bit lanes x 4 buckets each
    const int tid = threadIdx.x;
    if (tid == 0) { cLo = 0ull; cHi = 0ull; }
    __syncthreads();

    const long long base = (long long)blockIdx.x * EPB + (long long)tid * PER_THREAD;
    const vint4* p4 = (const vint4*)(ptrs + base);
    unsigned long long lo = 0, hi = 0;
#pragma unroll
    for (int k = 0; k < PER_THREAD / 4; ++k) {
        vint4 a = __builtin_nontemporal_load(p4 + k);
        {
            int b = a.x >> shift; b = b > (NB - 1) ? (NB - 1) : b;
            unsigned long long one = 1ull << (16 * (b & 3));
            if (b < 4) lo += one; else hi += one;
        }
        {
            int b = a.y >> shift; b = b > (NB - 1) ? (NB - 1) : b;
            unsigned long long one = 1ull << (16 * (b & 3));
            if (b < 4) lo += one; else hi += one;
        }
        {
            int b = a.z >> shift; b = b > (NB - 1) ? (NB - 1) : b;
            unsigned long long one = 1ull << (16 * (b & 3));
            if (b < 4) lo += one; else hi += one;
        }
        {
            int b = a.w >> shift; b = b > (NB - 1) ? (NB - 1) : b;
            unsigned long long one = 1ull << (16 * (b & 3));
            if (b < 4) lo += one; else hi += one;
        }
    }
    atomicAdd(&cLo, lo);
    atomicAdd(&cHi, hi);
    __syncthreads();
    if (tid < 4)
        counts[blockIdx.x * NB + tid] = (int)((cLo >> (16 * tid)) & 0xFFFFull);
    else if (tid < 8)
        counts[blockIdx.x * NB + tid] = (int)((cHi >> (16 * (tid - 4))) & 0xFFFFull);
}

// ---------------------------------------------------------------- Phase B
// One block per bucket: exclusive scan of counts[blk][b] over blk.
__global__ __launch_bounds__(THREADS) void phaseB_scan(
    const int* __restrict__ counts, int* __restrict__ offB,
    int* __restrict__ totals, int nblocks)
{
    __shared__ int wsum[THREADS / 64];
    const int b = blockIdx.x;
    const int tid = threadIdx.x, lane = tid & 63, wid = tid >> 6;
    const int per = nblocks / THREADS;
    const int start = tid * per;

    int s = 0;
    for (int i = 0; i < per; ++i) s += counts[(start + i) * NB + b];

    int inc = s;
#pragma unroll
    for (int d = 1; d < 64; d <<= 1) {
        int t = __shfl_up(inc, d);
        if (lane >= d) inc += t;
    }
    if (lane == 63) wsum[wid] = inc;
    __syncthreads();
    int wbase = 0;
    for (int w = 0; w < wid; ++w) wbase += wsum[w];
    int run = wbase + inc - s;   // exclusive prefix of this thread's chunk

    for (int i = 0; i < per; ++i) {
        int c = counts[(start + i) * NB + b];
        offB[(start + i) * NB + b] = run;
        run += c;
    }
    if (tid == THREADS - 1) totals[b] = run;
}

// ---------------------------------------------------------------- Phase C
// Stable partition of (ptr,csr) into NB bucket streams (order-preserving).
__global__ __launch_bounds__(THREADS) void phaseC_scatter(
    const int* __restrict__ ptrs, const int* __restrict__ csr,
    const int* __restrict__ offB, const int* __restrict__ totals,
    int* __restrict__ pairs, int shift)
{
    __shared__ int2 buf[EPB];                                   // 32 KB
    __shared__ unsigned long long wLo[THREADS / 64], wHi[THREADS / 64];
    __shared__ long long s_goff[NB];

    const int tid = threadIdx.x, lane = tid & 63, wid = tid >> 6;
    const long long base = (long long)blockIdx.x * EPB + (long long)tid * PER_THREAD;

    const vint4* p4 = (const vint4*)(ptrs + base);
    const vint4* c4 = (const vint4*)(csr + base);
    int p[PER_THREAD], c[PER_THREAD];
#pragma unroll
    for (int k = 0; k < PER_THREAD / 4; ++k) {
        vint4 a = __builtin_nontemporal_load(p4 + k);
        vint4 b = __builtin_nontemporal_load(c4 + k);
        p[4 * k + 0] = a.x; p[4 * k + 1] = a.y; p[4 * k + 2] = a.z; p[4 * k + 3] = a.w;
        c[4 * k + 0] = b.x; c[4 * k + 1] = b.y; c[4 * k + 2] = b.z; c[4 * k + 3] = b.w;
    }

    // Packed per-thread bucket counts: 16-bit lanes, buckets 0-3 in lo, 4-7 in hi.
    unsigned long long lo = 0, hi = 0;
#pragma unroll
    for (int j = 0; j < PER_THREAD; ++j) {
        int b = p[j] >> shift; b = b > (NB - 1) ? (NB - 1) : b;
        unsigned long long one = 1ull << (16 * (b & 3));
        if (b < 4) lo += one; else hi += one;
    }

    // Inclusive wave scan (lane-wise 16-bit adds never carry: sums <= 4096).
    unsigned long long vLo = lo, vHi = hi;
#pragma unroll
    for (int d = 1; d < 64; d <<= 1) {
        unsigned long long tLo = __shfl_up(vLo, (unsigned)d);
        unsigned long long tHi = __shfl_up(vHi, (unsigned)d);
        if (lane >= d) { vLo += tLo; vHi += tHi; }
    }
    if (lane == 63) { wLo[wid] = vLo; wHi[wid] = vHi; }

    // Global destination bases (8-entry padded so phase D vint4 loads align).
    if (tid < NB) {
        long long bs = 0;
        for (int i = 0; i < tid; ++i) bs = (bs + totals[i] + 7) & ~7ll;
        s_goff[tid] = bs + offB[blockIdx.x * NB + tid];
    }
    __syncthreads();

    unsigned long long wbLo = 0, wbHi = 0, gLo = 0, gHi = 0;
#pragma unroll
    for (int w = 0; w < THREADS / 64; ++w) {
        if (w < wid) { wbLo += wLo[w]; wbHi += wHi[w]; }
        gLo += wLo[w]; gHi += wHi[w];
    }
    const unsigned long long exLo = wbLo + vLo - lo;   // exclusive thread prefix
    const unsigned long long exHi = wbHi + vHi - hi;

    // Block-internal bucket bases from grand totals.
    unsigned long long obLo = 0, obHi = 0;
    int run = 0;
#pragma unroll
    for (int b = 0; b < NB; ++b) {
        unsigned long long r16 = (unsigned long long)(run & 0xFFFF);
        if (b < 4) obLo |= r16 << (16 * b); else obHi |= r16 << (16 * (b - 4));
        int tb = (b < 4) ? (int)((gLo >> (16 * b)) & 0xFFFFull)
                         : (int)((gHi >> (16 * (b - 4))) & 0xFFFFull);
        run += tb;
    }
    unsigned long long curLo = exLo + obLo;   // per-thread packed cursors
    unsigned long long curHi = exHi + obHi;

    // Replay in original order -> stable layout in LDS.
#pragma unroll
    for (int j = 0; j < PER_THREAD; ++j) {
        int b = p[j] >> shift; b = b > (NB - 1) ? (NB - 1) : b;
        int sh = 16 * (b & 3);
        int idx = (b < 4) ? (int)((curLo >> sh) & 0xFFFFull)
                          : (int)((curHi >> sh) & 0xFFFFull);
        buf[idx] = make_int2(p[j], c[j]);
        if (b < 4) curLo += 1ull << sh; else curHi += 1ull << sh;
    }
    __syncthreads();

    // Coalesced copy-out of the 8 contiguous bucket regions.
#pragma unroll
    for (int b = 0; b < NB; ++b) {
        int bib = (b < 4) ? (int)((obLo >> (16 * b)) & 0xFFFFull)
                          : (int)((obHi >> (16 * (b - 4))) & 0xFFFFull);
        int tb  = (b < 4) ? (int)((gLo >> (16 * b)) & 0xFFFFull)
                          : (int)((gHi >> (16 * (b - 4))) & 0xFFFFull);
        long long go = s_goff[b];
        for (int i = tid; i < tb; i += THREADS) {
            int2 v = buf[bib + i];
            vint2 w; w.x = v.x; w.y = v.y;
            __builtin_nontemporal_store(w, (vint2*)(pairs + 2 * (go + i)));
        }
    }
}

// ---------------------------------------------------------------- Phase D
// bucket = blockIdx % 8 -> XCD pinning (round-robin dispatch) -> 4 MB slice
// of x stays L2-resident. csr sorted within bucket -> LDS run-length.
__global__ __launch_bounds__(THREADS) void phaseD_gather(
    const float* __restrict__ x, const int* __restrict__ pairs,
    const int* __restrict__ totals, float* __restrict__ out)
{
    __shared__ float seg[LDS_SEGS_D];            // 48 KB -> 3 blocks/CU
    __shared__ int s_sb, s_sl;

    const int tid = threadIdx.x;
    const int b = blockIdx.x & (NB - 1);
    const long long strideChunks = gridDim.x / NB;

    long long bbase = 0;
#pragma unroll
    for (int i = 0; i < NB; ++i)
        if (i < b) bbase = (bbase + totals[i] + 7) & ~7ll;   // match phase C padding
    const long long total_b = totals[b];

    for (long long j = blockIdx.x >> 3; j * EPB < total_b; j += strideChunks) {
        const long long off = bbase + j * EPB;
        const long long rem = total_b - j * EPB;
        const int n = rem < (long long)EPB ? (int)rem : EPB;

        for (int s = tid; s < LDS_SEGS_D; s += THREADS) seg[s] = 0.0f;
        if (tid == 0) {
            s_sb = pairs[2 * off + 1];
            s_sl = pairs[2 * (off + n - 1) + 1];
        }
        __syncthreads();
        const int sbase = s_sb;
        const int span = s_sl - sbase + 1;
        const bool fits = (span <= LDS_SEGS_D);   // block-uniform

        const int i0 = tid * PER_THREAD;
        float acc = 0.0f; int cur = -1;
        if (i0 + PER_THREAD <= n) {
            const vint4* q = (const vint4*)(pairs + 2 * (off + i0));
            int pp[PER_THREAD], cc[PER_THREAD];
#pragma unroll
            for (int k = 0; k < PER_THREAD / 2; ++k) {   // 8 x vint4 = 16 pairs
                vint4 t = __builtin_nontemporal_load(q + k);
                pp[2 * k] = t.x; cc[2 * k] = t.y;
                pp[2 * k + 1] = t.z; cc[2 * k + 1] = t.w;
            }
            float v[PER_THREAD];
#pragma unroll
            for (int jj = 0; jj < PER_THREAD; ++jj) v[jj] = x[pp[jj]];   // L2-hit gathers
            acc = v[0]; cur = cc[0];
#pragma unroll
            for (int jj = 1; jj < PER_THREAD; ++jj) {
                if (cc[jj] == cur) acc += v[jj];
                else {
                    if (fits) atomicAdd(&seg[cur - sbase], acc);
                    else      atomicAdd(out + cur, acc);
                    cur = cc[jj]; acc = v[jj];
                }
            }
        } else if (i0 < n) {
            for (int e = i0; e < n; ++e) {
                int pp = pairs[2 * (off + e)];
                int cc = pairs[2 * (off + e) + 1];
                float v = x[pp];
                if (cc == cur) acc += v;
                else {
                    if (cur >= 0) {
                        if (fits) atomicAdd(&seg[cur - sbase], acc);
                        else      atomicAdd(out + cur, acc);
                    }
                    cur = cc; acc = v;
                }
            }
        }
        if (cur >= 0) {
            if (fits) atomicAdd(&seg[cur - sbase], acc);
            else      atomicAdd(out + cur, acc);
        }

        __syncthreads();
        if (fits) {
            for (int s = tid; s < span; s += THREADS) {
                float val = seg[s];
                if (val != 0.0f) atomicAdd(out + sbase + s, val);   // buckets overlap
            }
        }
        __syncthreads();
    }
}

// ------------------------------------------------- Fallback (= proven R3)
__global__ __launch_bounds__(THREADS) void fallback_segsum(
    const float* __restrict__ x, const int* __restrict__ ptrs,
    const int* __restrict__ csr, float* __restrict__ out)
{
    __shared__ float seg[LDS_SEGS_FB];
    const int tid = threadIdx.x;
    const long long blk_base = (long long)blockIdx.x * EPB;
    const long long base = blk_base + (long long)tid * PER_THREAD;

    const int seg_base = csr[blk_base];
    const int seg_last = csr[blk_base + EPB - 1];
    const int span = seg_last - seg_base + 1;

    for (int s = tid; s < LDS_SEGS_FB; s += THREADS) seg[s] = 0.0f;

    const vint4* p4 = (const vint4*)(ptrs + base);
    const vint4* c4 = (const vint4*)(csr + base);
    int p[PER_THREAD], c[PER_THREAD];
#pragma unroll
    for (int k = 0; k < PER_THREAD / 4; ++k) {
        vint4 a = __builtin_nontemporal_load(p4 + k);
        vint4 b = __builtin_nontemporal_load(c4 + k);
        p[4 * k + 0] = a.x; p[4 * k + 1] = a.y; p[4 * k + 2] = a.z; p[4 * k + 3] = a.w;
        c[4 * k + 0] = b.x; c[4 * k + 1] = b.y; c[4 * k + 2] = b.z; c[4 * k + 3] = b.w;
    }
    float v[PER_THREAD];
#pragma unroll
    for (int j = 0; j < PER_THREAD; ++j) v[j] = x[p[j]];
    __syncthreads();

    if (span <= LDS_SEGS_FB) {
        float acc = v[0]; int cur = c[0];
#pragma unroll
        for (int j = 1; j < PER_THREAD; ++j) {
            if (c[j] == cur) acc += v[j];
            else { atomicAdd(&seg[cur - seg_base], acc); cur = c[j]; acc = v[j]; }
        }
        atomicAdd(&seg[cur - seg_base], acc);
        __syncthreads();
        for (int s = tid; s < span; s += THREADS) {
            const int g = seg_base + s;
            const float val = seg[s];
            if (s == 0 || g == seg_last) { if (val != 0.0f) atomicAdd(out + g, val); }
            else __builtin_nontemporal_store(val, out + g);
        }
    } else {
        float acc = v[0]; int cur = c[0];
#pragma unroll
        for (int j = 1; j < PER_THREAD; ++j) {
            if (c[j] == cur) acc += v[j];
            else { atomicAdd(out + cur, acc); cur = c[j]; acc = v[j]; }
        }
        atomicAdd(out + cur, acc);
    }
}

extern "C" void kernel_launch(void* const* d_in, const int* in_sizes, int n_in,
                              void* d_out, int out_size, void* d_ws, size_t ws_size,
                              hipStream_t stream) {
    const float* x    = (const float*)d_in[0];
    const int*   ptrs = (const int*)d_in[1];
    const int*   csr  = (const int*)d_in[2];
    float*       out  = (float*)d_out;

    const long long nnz = in_sizes[1];            // 33,554,432
    const int x_size = in_sizes[0];               // 8,388,608
    const long long nblocks = nnz / EPB;          // 8,192

    (void)hipMemsetAsync(d_out, 0, (size_t)out_size * sizeof(float), stream);

    const size_t pairsBytes = (size_t)nnz * 8 + 64 * NB;   // + padding slack
    const size_t cntBytes = (size_t)nblocks * NB * sizeof(int);
    const size_t need = pairsBytes + 2 * cntBytes + NB * sizeof(int) + 64;
    const int slice = x_size / NB;
    const bool pow2slice = slice > 0 && (slice & (slice - 1)) == 0;

    if (ws_size >= need && (nnz % EPB) == 0 && (nblocks % THREADS) == 0 &&
        pow2slice && (x_size % NB) == 0) {
        char* w = (char*)d_ws;
        int* pairs  = (int*)w;
        int* counts = (int*)(w + pairsBytes);
        int* offB   = (int*)(w + pairsBytes + cntBytes);
        int* totals = (int*)(w + pairsBytes + 2 * cntBytes);
        const int shift = __builtin_ctz((unsigned)slice);   // 20

        phaseA_count <<<(int)nblocks, THREADS, 0, stream>>>(ptrs, counts, shift);
        phaseB_scan  <<<NB,           THREADS, 0, stream>>>(counts, offB, totals, (int)nblocks);
        phaseC_scatter<<<(int)nblocks, THREADS, 0, stream>>>(ptrs, csr, offB, totals, pairs, shift);
        phaseD_gather<<<(int)nblocks, THREADS, 0, stream>>>(x, pairs, totals, out);
    } else {
        fallback_segsum<<<(int)nblocks, THREADS, 0, stream>>>(x, ptrs, csr, out);
    }
}